// Round 9
// baseline (189.161 us; speedup 1.0000x reference)
//
#include <hip/hip_runtime.h>
#include <math.h>

#define EPSV 1e-4f
#define SCHUNK 32

// Relaxed agent-scope atomics: point-wise LLC-coherent accesses (sc1), NO
// cache-wide invalidate/writeback (acquire/release emit buffer_inv/buffer_wbl2
// on gfx950 -> measured 693us disaster in round 1). Ordering done manually
// with s_waitcnt vmcnt(0) before flag stores.
__device__ __forceinline__ float agent_load_f(const float* p) {
    return __hip_atomic_load(p, __ATOMIC_RELAXED, __HIP_MEMORY_SCOPE_AGENT);
}
__device__ __forceinline__ void agent_store_f(float* p, float v) {
    __hip_atomic_store(p, v, __ATOMIC_RELAXED, __HIP_MEMORY_SCOPE_AGENT);
}
__device__ __forceinline__ int agent_load_i(const int* p) {
    return __hip_atomic_load(p, __ATOMIC_RELAXED, __HIP_MEMORY_SCOPE_AGENT);
}
__device__ __forceinline__ void agent_store_i(int* p, int v) {
    __hip_atomic_store(p, v, __ATOMIC_RELAXED, __HIP_MEMORY_SCOPE_AGENT);
}

// ---------------- clear: flags + ticket ----------------
__global__ void clear_kernel(int* __restrict__ flags, int n) {
    int i = blockIdx.x * blockDim.x + threadIdx.x;
    if (i < n) flags[i] = 0;
}

// ---------------- b_flat scan chain (round-2 proven, verbatim) ----------------
__global__ void scan_sum_kernel(const int* __restrict__ b, int n,
                                int* __restrict__ bsum) {
    __shared__ int red[256];
    int tid = threadIdx.x;
    int base = blockIdx.x * 1024 + tid * 4;
    int s = 0;
#pragma unroll
    for (int k = 0; k < 4; ++k) {
        int j = base + k;
        if (j < n) s += b[j];
    }
    red[tid] = s;
    __syncthreads();
    for (int off = 128; off > 0; off >>= 1) {
        if (tid < off) red[tid] += red[tid + off];
        __syncthreads();
    }
    if (tid == 0) bsum[blockIdx.x] = red[0];
}

__global__ void scan_offsets_kernel(const int* __restrict__ bsum,
                                    int* __restrict__ boff, int nb) {
    __shared__ int sh[1024];
    int i = threadIdx.x;
    int v = (i < nb) ? bsum[i] : 0;
    sh[i] = v;
    __syncthreads();
    for (int off = 1; off < 1024; off <<= 1) {
        int t = sh[i];
        if (i >= off) t += sh[i - off];
        __syncthreads();
        sh[i] = t;
        __syncthreads();
    }
    if (i < nb) boff[i] = sh[i] - v;
}

__global__ void scan_emit_kernel(const int* __restrict__ b, int n,
                                 const int* __restrict__ boff,
                                 int* __restrict__ sidx, int L, int Louter) {
    __shared__ int red[256];
    int tid = threadIdx.x;
    int base = blockIdx.x * 1024 + tid * 4;
    int v[4];
    int s = 0;
#pragma unroll
    for (int k = 0; k < 4; ++k) {
        int j = base + k;
        v[k] = (j < n) ? b[j] : 0;
        s += v[k];
    }
    red[tid] = s;
    __syncthreads();
    for (int off = 1; off < 256; off <<= 1) {
        int t = red[tid];
        if (tid >= off) t += red[tid - off];
        __syncthreads();
        red[tid] = t;
        __syncthreads();
    }
    int cum = red[tid] - s + boff[blockIdx.x];
#pragma unroll
    for (int k = 0; k < 4; ++k) {
        int j = base + k;
        if (j < n) {
            cum += v[k];
            if (v[k] > 0) {
                int t = cum - 1;
                if (t >= 0 && t < L) sidx[t] = j;
            }
        }
    }
    if (base == 0 && blockIdx.x == 0) sidx[L] = Louter;
}

// ---------------- single-pass decoupled-lookback scan + scatter ----------------
// r7 structure (best: 180.3us) with ONE variable changed: SCHUNK 64->32 so the
// register budget fits under a 64-VGPR cap -> __launch_bounds__(512,8) = 32
// waves/CU (r7 ran 16 w/CU at (512,4)). z[32]+hb[8]+~18 scalars ~= 58 VGPR.
// Trade: NC 2048->4096 (2x block prologues), lookback depth ~2->~3-4
// (P/chunk ~ e^-32; prodAcc flushes to 0 in 3-4 steps). Probes whether r7's
// residual 25% over the traffic floor is occupancy-limited latency hiding.
// Thread 0 alone spins (relaxed). Deadlock-free: ticket => predecessors
// resident; aggregate+flag published before any wait.
__global__ __launch_bounds__(512, 8) void scan_lookback_kernel(
        const float* __restrict__ h,
        const float* __restrict__ psel,
        const int* __restrict__ seq,
        const int* __restrict__ sidx,
        float* __restrict__ out,
        float* __restrict__ aggE,   // [NC][d]
        float* __restrict__ aggP,   // [NC]
        int* __restrict__ flags,    // [NC] flags, flags[NC] = ticket
        int L, int d, int Louter, int NC) {
    __shared__ float sh_a[SCHUNK];
    __shared__ float sh_p[SCHUNK];
    __shared__ float sh_A[SCHUNK];   // A_t = prod_{u<=t} a_u
    __shared__ int   sh_j[SCHUNK + 1];
    __shared__ int   sh_g;
    __shared__ float sh_Pbr;

    const int tid = threadIdx.x;
    if (tid == 0) sh_g = atomicAdd(&flags[NC], 1);  // device-scope ticket
    __syncthreads();
    const int g  = sh_g;
    const int t0 = g * SCHUNK;
    const int nt = min(SCHUNK, L - t0);

    // prologue: per-timestep scalars (fused prep) + scatter ranges into LDS
    if (tid < nt) {
        int t = t0 + tid;
        float p = psel[t];
        p = fminf(fmaxf(p, EPSV), 1.0f - EPSV);
        bool start = (t == 0) || (seq[t] != seq[t - 1]);
        sh_a[tid] = start ? 0.0f : (1.0f - p);   // exp(-dt) == 1-p exactly
        sh_p[tid] = p;                           // b_t = p*h
    }
    if (tid <= nt) sh_j[tid] = sidx[t0 + tid];   // sidx[L] sentinel exists
    __syncthreads();

    // lanes 0..31 log-step inclusive prefix-product -> sh_A (5 shfl_up steps)
    if (tid < SCHUNK) {
        float v = (tid < nt) ? sh_a[tid] : 1.0f;
#pragma unroll
        for (int off = 1; off < SCHUNK; off <<= 1) {
            float w = __shfl_up(v, off);
            if (tid >= off) v *= w;
        }
        sh_A[tid] = v;
    }
    __syncthreads();

    const int c = tid;
    const float* __restrict__ hp = h + (size_t)t0 * d + c;
    const bool full = (nt == SCHUNK);

    // ---- pass 1: local scan fully in registers, h read ONCE (nontemporal) ----
    float z[SCHUNK];
    float st = 0.0f;
    if (full) {
#pragma unroll
        for (int grp = 0; grp < SCHUNK / 8; ++grp) {
            float hb[8];
#pragma unroll
            for (int k = 0; k < 8; ++k)
                hb[k] = __builtin_nontemporal_load(hp + (size_t)(grp * 8 + k) * d);
#pragma unroll
            for (int k = 0; k < 8; ++k) {
                int t = grp * 8 + k;
                st = fmaf(sh_a[t], st, sh_p[t] * hb[k]);
                z[t] = st;                       // static index -> stays in VGPR
            }
        }
    } else {
        for (int t = 0; t < nt; ++t)
            st = fmaf(sh_a[t], st, sh_p[t] * hp[(size_t)t * d]);
    }

    // ---- publish aggregate (relaxed + waitcnt ordering) ----
    agent_store_f(&aggE[(size_t)g * d + c], st);
    __syncthreads();            // drains vmcnt -> all aggE stores complete
    if (tid == 0) {
        agent_store_f(&aggP[g], sh_A[nt - 1]);
        asm volatile("s_waitcnt vmcnt(0)" ::: "memory");  // aggP before flag
        agent_store_i(&flags[g], 1);
    }

    // ---- decoupled lookback: carry = state at end of chunk g-1 ----
    float carry = 0.0f;
    float prodAcc = 1.0f;
    for (int i = g - 1; i >= 0; --i) {
        if (tid == 0) {
            while (agent_load_i(&flags[i]) == 0) __builtin_amdgcn_s_sleep(1);
            sh_Pbr = agent_load_f(&aggP[i]);
        }
        __syncthreads();
        float Pi = sh_Pbr;
        carry = fmaf(prodAcc, agent_load_f(&aggE[(size_t)i * d + c]), carry);
        prodAcc *= Pi;                    // uniform across threads
        __syncthreads();                  // sh_Pbr reused next iteration
        if (prodAcc == 0.0f) break;       // e^-32/chunk -> 0 after ~3-4 steps
    }

    // ---- pass 2: register-only finalize y_t = A_t*carry + z_t, scatter ----
    if (full) {
#pragma unroll
        for (int t = 0; t < SCHUNK; ++t) {
            float y = fmaf(sh_A[t], carry, z[t]);
            int j0 = max(sh_j[t], 0);
            int j1 = min(sh_j[t + 1], Louter);
            for (int j = j0; j < j1; ++j)
                __builtin_nontemporal_store(y, out + (size_t)j * d + c);
        }
    } else {
        // tail chunk (not hit when L%32==0): rescan with carry folded in
        float s2 = carry;
        for (int t = 0; t < nt; ++t) {
            s2 = fmaf(sh_a[t], s2, sh_p[t] * hp[(size_t)t * d]);
            int j0 = max(sh_j[t], 0);
            int j1 = min(sh_j[t + 1], Louter);
            for (int j = j0; j < j1; ++j)
                out[(size_t)j * d + c] = s2;
        }
    }
}

extern "C" void kernel_launch(void* const* d_in, const int* in_sizes, int n_in,
                              void* d_out, int out_size, void* d_ws, size_t ws_size,
                              hipStream_t stream) {
    const float* h     = (const float*)d_in[0];
    const int*   bflat = (const int*)d_in[1];
    const float* psel  = (const float*)d_in[2];
    const int*   seq   = (const int*)d_in[3];
    float* out = (float*)d_out;

    const int L      = in_sizes[2];          // 131072
    const int Louter = in_sizes[1];          // 262144
    const int d      = in_sizes[0] / L;      // 512

    const int NC = (L + SCHUNK - 1) / SCHUNK;   // 4096
    const int nb = (Louter + 1023) / 1024;      // 256 scan blocks

    // workspace layout (256B-aligned slices) — total ~9 MB
    char* ws = (char*)d_ws;
    size_t off = 0;
    auto alloc = [&](size_t bytes) -> void* {
        void* p = ws + off;
        off = (off + bytes + 255) & ~(size_t)255;
        return p;
    };
    float* aggE  = (float*)alloc((size_t)NC * d * 4);
    float* aggP  = (float*)alloc((size_t)NC * 4);
    int*   flags = (int*)alloc((size_t)(NC + 1) * 4);   // +1 = ticket
    int*   bsum  = (int*)alloc((size_t)nb * 4);
    int*   boff  = (int*)alloc((size_t)nb * 4);
    int*   sidx  = (int*)alloc((size_t)(L + 1) * 4);
    (void)ws_size;

    clear_kernel<<<(NC + 1 + 255) / 256, 256, 0, stream>>>(flags, NC + 1);

    scan_sum_kernel<<<nb, 256, 0, stream>>>(bflat, Louter, bsum);
    scan_offsets_kernel<<<1, 1024, 0, stream>>>(bsum, boff, nb);
    scan_emit_kernel<<<nb, 256, 0, stream>>>(bflat, Louter, boff, sidx, L, Louter);

    scan_lookback_kernel<<<NC, d, 0, stream>>>(h, psel, seq, sidx, out,
                                               aggE, aggP, flags,
                                               L, d, Louter, NC);
}

// Round 10
// 182.819 us; speedup vs baseline: 1.0347x; 1.0347x over previous
//
#include <hip/hip_runtime.h>
#include <math.h>

#define EPSV 1e-4f
#define SCHUNK 128

// Relaxed agent-scope atomics: point-wise LLC-coherent accesses (sc1), NO
// cache-wide invalidate/writeback (acquire/release emit buffer_inv/buffer_wbl2
// on gfx950 -> measured 693us disaster in round 1). Ordering done manually
// with s_waitcnt vmcnt(0) before flag stores.
__device__ __forceinline__ float agent_load_f(const float* p) {
    return __hip_atomic_load(p, __ATOMIC_RELAXED, __HIP_MEMORY_SCOPE_AGENT);
}
__device__ __forceinline__ void agent_store_f(float* p, float v) {
    __hip_atomic_store(p, v, __ATOMIC_RELAXED, __HIP_MEMORY_SCOPE_AGENT);
}
__device__ __forceinline__ int agent_load_i(const int* p) {
    return __hip_atomic_load(p, __ATOMIC_RELAXED, __HIP_MEMORY_SCOPE_AGENT);
}
__device__ __forceinline__ void agent_store_i(int* p, int v) {
    __hip_atomic_store(p, v, __ATOMIC_RELAXED, __HIP_MEMORY_SCOPE_AGENT);
}

// ---------------- clear: flags + ticket ----------------
__global__ void clear_kernel(int* __restrict__ flags, int n) {
    int i = blockIdx.x * blockDim.x + threadIdx.x;
    if (i < n) flags[i] = 0;
}

// ---------------- b_flat scan chain (round-2 proven, verbatim) ----------------
__global__ void scan_sum_kernel(const int* __restrict__ b, int n,
                                int* __restrict__ bsum) {
    __shared__ int red[256];
    int tid = threadIdx.x;
    int base = blockIdx.x * 1024 + tid * 4;
    int s = 0;
#pragma unroll
    for (int k = 0; k < 4; ++k) {
        int j = base + k;
        if (j < n) s += b[j];
    }
    red[tid] = s;
    __syncthreads();
    for (int off = 128; off > 0; off >>= 1) {
        if (tid < off) red[tid] += red[tid + off];
        __syncthreads();
    }
    if (tid == 0) bsum[blockIdx.x] = red[0];
}

__global__ void scan_offsets_kernel(const int* __restrict__ bsum,
                                    int* __restrict__ boff, int nb) {
    __shared__ int sh[1024];
    int i = threadIdx.x;
    int v = (i < nb) ? bsum[i] : 0;
    sh[i] = v;
    __syncthreads();
    for (int off = 1; off < 1024; off <<= 1) {
        int t = sh[i];
        if (i >= off) t += sh[i - off];
        __syncthreads();
        sh[i] = t;
        __syncthreads();
    }
    if (i < nb) boff[i] = sh[i] - v;
}

__global__ void scan_emit_kernel(const int* __restrict__ b, int n,
                                 const int* __restrict__ boff,
                                 int* __restrict__ sidx, int L, int Louter) {
    __shared__ int red[256];
    int tid = threadIdx.x;
    int base = blockIdx.x * 1024 + tid * 4;
    int v[4];
    int s = 0;
#pragma unroll
    for (int k = 0; k < 4; ++k) {
        int j = base + k;
        v[k] = (j < n) ? b[j] : 0;
        s += v[k];
    }
    red[tid] = s;
    __syncthreads();
    for (int off = 1; off < 256; off <<= 1) {
        int t = red[tid];
        if (tid >= off) t += red[tid - off];
        __syncthreads();
        red[tid] = t;
        __syncthreads();
    }
    int cum = red[tid] - s + boff[blockIdx.x];
#pragma unroll
    for (int k = 0; k < 4; ++k) {
        int j = base + k;
        if (j < n) {
            cum += v[k];
            if (v[k] > 0) {
                int t = cum - 1;
                if (t >= 0 && t < L) sidx[t] = j;
            }
        }
    }
    if (base == 0 && blockIdx.x == 0) sidx[L] = Louter;
}

// ---------------- single-pass decoupled-lookback scan + scatter ----------------
// r7 structure (best: 180.3us) pushed along the winning chunk-size axis
// (16->32->64 gave 216->189->180): SCHUNK=128, z[128] entirely in VGPRs.
// VGPR ~= 128(z)+8(hb)+~15 scalars ~= 150 -> __launch_bounds__(512,3) (~170
// cap), 8 waves/CU. MLP: 8 waves x 8 outstanding x 256B = 16KB in flight/CU,
// enough to saturate HBM (r7>r9 proved occupancy isn't binding). NC=1024:
// half the block prologue/publish/lookback overhead of r7, and P/chunk ~
// e^-128 flushes to EXACT fp32 zero -> lookback terminates after ONE step.
// Thread 0 alone spins (relaxed). Deadlock-free: ticket => predecessors
// resident; aggregate+flag published before any wait.
__global__ __launch_bounds__(512, 3) void scan_lookback_kernel(
        const float* __restrict__ h,
        const float* __restrict__ psel,
        const int* __restrict__ seq,
        const int* __restrict__ sidx,
        float* __restrict__ out,
        float* __restrict__ aggE,   // [NC][d]
        float* __restrict__ aggP,   // [NC]
        int* __restrict__ flags,    // [NC] flags, flags[NC] = ticket
        int L, int d, int Louter, int NC) {
    __shared__ float sh_a[SCHUNK];
    __shared__ float sh_p[SCHUNK];
    __shared__ float sh_A[SCHUNK];   // A_t = prod_{u<=t} a_u
    __shared__ int   sh_j[SCHUNK + 1];
    __shared__ int   sh_g;
    __shared__ float sh_Pbr;

    const int tid = threadIdx.x;
    if (tid == 0) sh_g = atomicAdd(&flags[NC], 1);  // device-scope ticket
    __syncthreads();
    const int g  = sh_g;
    const int t0 = g * SCHUNK;
    const int nt = min(SCHUNK, L - t0);

    // prologue: per-timestep scalars (fused prep) + scatter ranges into LDS
    if (tid < nt) {
        int t = t0 + tid;
        float p = psel[t];
        p = fminf(fmaxf(p, EPSV), 1.0f - EPSV);
        bool start = (t == 0) || (seq[t] != seq[t - 1]);
        sh_a[tid] = start ? 0.0f : (1.0f - p);   // exp(-dt) == 1-p exactly
        sh_p[tid] = p;                           // b_t = p*h
    }
    if (tid <= nt) sh_j[tid] = sidx[t0 + tid];   // sidx[L] sentinel exists
    __syncthreads();

    // 2-wave prefix-product -> sh_A: per-wave shfl_up scan + cross-wave fixup
    if (tid < SCHUNK) {
        float v = (tid < nt) ? sh_a[tid] : 1.0f;
        int lane = tid & 63;
#pragma unroll
        for (int off = 1; off < 64; off <<= 1) {
            float w = __shfl_up(v, off);
            if (lane >= off) v *= w;
        }
        sh_A[tid] = v;
    }
    __syncthreads();
    if (tid >= 64 && tid < SCHUNK) {
        float fix = sh_A[63];                    // total of wave 0's segment
        sh_A[tid] *= fix;                        // benign: all lanes same RMW order
    }
    __syncthreads();

    const int c = tid;
    const float* __restrict__ hp = h + (size_t)t0 * d + c;
    const bool full = (nt == SCHUNK);

    // ---- pass 1: local scan fully in registers, h read ONCE (nontemporal) ----
    float z[SCHUNK];
    float st = 0.0f;
    if (full) {
#pragma unroll
        for (int grp = 0; grp < SCHUNK / 8; ++grp) {
            float hb[8];
#pragma unroll
            for (int k = 0; k < 8; ++k)
                hb[k] = __builtin_nontemporal_load(hp + (size_t)(grp * 8 + k) * d);
#pragma unroll
            for (int k = 0; k < 8; ++k) {
                int t = grp * 8 + k;
                st = fmaf(sh_a[t], st, sh_p[t] * hb[k]);
                z[t] = st;                       // static index -> stays in VGPR
            }
        }
    } else {
        for (int t = 0; t < nt; ++t)
            st = fmaf(sh_a[t], st, sh_p[t] * hp[(size_t)t * d]);
    }

    // ---- publish aggregate (relaxed + waitcnt ordering) ----
    agent_store_f(&aggE[(size_t)g * d + c], st);
    __syncthreads();            // drains vmcnt -> all aggE stores complete
    if (tid == 0) {
        agent_store_f(&aggP[g], sh_A[nt - 1]);
        asm volatile("s_waitcnt vmcnt(0)" ::: "memory");  // aggP before flag
        agent_store_i(&flags[g], 1);
    }

    // ---- decoupled lookback: carry = state at end of chunk g-1 ----
    float carry = 0.0f;
    float prodAcc = 1.0f;
    for (int i = g - 1; i >= 0; --i) {
        if (tid == 0) {
            while (agent_load_i(&flags[i]) == 0) __builtin_amdgcn_s_sleep(1);
            sh_Pbr = agent_load_f(&aggP[i]);
        }
        __syncthreads();
        float Pi = sh_Pbr;
        carry = fmaf(prodAcc, agent_load_f(&aggE[(size_t)i * d + c]), carry);
        prodAcc *= Pi;                    // uniform across threads
        __syncthreads();                  // sh_Pbr reused next iteration
        if (prodAcc == 0.0f) break;       // e^-128/chunk == fp32 0 -> 1 step
    }

    // ---- pass 2: register-only finalize y_t = A_t*carry + z_t, scatter ----
    if (full) {
#pragma unroll
        for (int t = 0; t < SCHUNK; ++t) {
            float y = fmaf(sh_A[t], carry, z[t]);
            int j0 = max(sh_j[t], 0);
            int j1 = min(sh_j[t + 1], Louter);
            for (int j = j0; j < j1; ++j)
                __builtin_nontemporal_store(y, out + (size_t)j * d + c);
        }
    } else {
        // tail chunk (not hit when L%128==0): rescan with carry folded in
        float s2 = carry;
        for (int t = 0; t < nt; ++t) {
            s2 = fmaf(sh_a[t], s2, sh_p[t] * hp[(size_t)t * d]);
            int j0 = max(sh_j[t], 0);
            int j1 = min(sh_j[t + 1], Louter);
            for (int j = j0; j < j1; ++j)
                out[(size_t)j * d + c] = s2;
        }
    }
}

extern "C" void kernel_launch(void* const* d_in, const int* in_sizes, int n_in,
                              void* d_out, int out_size, void* d_ws, size_t ws_size,
                              hipStream_t stream) {
    const float* h     = (const float*)d_in[0];
    const int*   bflat = (const int*)d_in[1];
    const float* psel  = (const float*)d_in[2];
    const int*   seq   = (const int*)d_in[3];
    float* out = (float*)d_out;

    const int L      = in_sizes[2];          // 131072
    const int Louter = in_sizes[1];          // 262144
    const int d      = in_sizes[0] / L;      // 512

    const int NC = (L + SCHUNK - 1) / SCHUNK;   // 1024
    const int nb = (Louter + 1023) / 1024;      // 256 scan blocks

    // workspace layout (256B-aligned slices) — total ~2.7 MB
    char* ws = (char*)d_ws;
    size_t off = 0;
    auto alloc = [&](size_t bytes) -> void* {
        void* p = ws + off;
        off = (off + bytes + 255) & ~(size_t)255;
        return p;
    };
    float* aggE  = (float*)alloc((size_t)NC * d * 4);
    float* aggP  = (float*)alloc((size_t)NC * 4);
    int*   flags = (int*)alloc((size_t)(NC + 1) * 4);   // +1 = ticket
    int*   bsum  = (int*)alloc((size_t)nb * 4);
    int*   boff  = (int*)alloc((size_t)nb * 4);
    int*   sidx  = (int*)alloc((size_t)(L + 1) * 4);
    (void)ws_size;

    clear_kernel<<<(NC + 1 + 255) / 256, 256, 0, stream>>>(flags, NC + 1);

    scan_sum_kernel<<<nb, 256, 0, stream>>>(bflat, Louter, bsum);
    scan_offsets_kernel<<<1, 1024, 0, stream>>>(bsum, boff, nb);
    scan_emit_kernel<<<nb, 256, 0, stream>>>(bflat, Louter, boff, sidx, L, Louter);

    scan_lookback_kernel<<<NC, d, 0, stream>>>(h, psel, seq, sidx, out,
                                               aggE, aggP, flags,
                                               L, d, Louter, NC);
}

// Round 11
// 181.996 us; speedup vs baseline: 1.0394x; 1.0045x over previous
//
#include <hip/hip_runtime.h>
#include <math.h>

#define EPSV 1e-4f
#define SCHUNK 64

// Relaxed agent-scope atomics: point-wise LLC-coherent accesses (sc1), NO
// cache-wide invalidate/writeback (acquire/release emit buffer_inv/buffer_wbl2
// on gfx950 -> measured 693us disaster in round 1). Ordering done manually
// with s_waitcnt vmcnt(0) before flag stores.
__device__ __forceinline__ float agent_load_f(const float* p) {
    return __hip_atomic_load(p, __ATOMIC_RELAXED, __HIP_MEMORY_SCOPE_AGENT);
}
__device__ __forceinline__ void agent_store_f(float* p, float v) {
    __hip_atomic_store(p, v, __ATOMIC_RELAXED, __HIP_MEMORY_SCOPE_AGENT);
}
__device__ __forceinline__ int agent_load_i(const int* p) {
    return __hip_atomic_load(p, __ATOMIC_RELAXED, __HIP_MEMORY_SCOPE_AGENT);
}
__device__ __forceinline__ void agent_store_i(int* p, int v) {
    __hip_atomic_store(p, v, __ATOMIC_RELAXED, __HIP_MEMORY_SCOPE_AGENT);
}

// ---------------- clear: flags + ticket ----------------
__global__ void clear_kernel(int* __restrict__ flags, int n) {
    int i = blockIdx.x * blockDim.x + threadIdx.x;
    if (i < n) flags[i] = 0;
}

// ---------------- b_flat scan chain (round-2 proven, verbatim) ----------------
__global__ void scan_sum_kernel(const int* __restrict__ b, int n,
                                int* __restrict__ bsum) {
    __shared__ int red[256];
    int tid = threadIdx.x;
    int base = blockIdx.x * 1024 + tid * 4;
    int s = 0;
#pragma unroll
    for (int k = 0; k < 4; ++k) {
        int j = base + k;
        if (j < n) s += b[j];
    }
    red[tid] = s;
    __syncthreads();
    for (int off = 128; off > 0; off >>= 1) {
        if (tid < off) red[tid] += red[tid + off];
        __syncthreads();
    }
    if (tid == 0) bsum[blockIdx.x] = red[0];
}

__global__ void scan_offsets_kernel(const int* __restrict__ bsum,
                                    int* __restrict__ boff, int nb) {
    __shared__ int sh[1024];
    int i = threadIdx.x;
    int v = (i < nb) ? bsum[i] : 0;
    sh[i] = v;
    __syncthreads();
    for (int off = 1; off < 1024; off <<= 1) {
        int t = sh[i];
        if (i >= off) t += sh[i - off];
        __syncthreads();
        sh[i] = t;
        __syncthreads();
    }
    if (i < nb) boff[i] = sh[i] - v;
}

__global__ void scan_emit_kernel(const int* __restrict__ b, int n,
                                 const int* __restrict__ boff,
                                 int* __restrict__ sidx, int L, int Louter) {
    __shared__ int red[256];
    int tid = threadIdx.x;
    int base = blockIdx.x * 1024 + tid * 4;
    int v[4];
    int s = 0;
#pragma unroll
    for (int k = 0; k < 4; ++k) {
        int j = base + k;
        v[k] = (j < n) ? b[j] : 0;
        s += v[k];
    }
    red[tid] = s;
    __syncthreads();
    for (int off = 1; off < 256; off <<= 1) {
        int t = red[tid];
        if (tid >= off) t += red[tid - off];
        __syncthreads();
        red[tid] = t;
        __syncthreads();
    }
    int cum = red[tid] - s + boff[blockIdx.x];
#pragma unroll
    for (int k = 0; k < 4; ++k) {
        int j = base + k;
        if (j < n) {
            cum += v[k];
            if (v[k] > 0) {
                int t = cum - 1;
                if (t >= 0 && t < L) sidx[t] = j;
            }
        }
    }
    if (base == 0 && blockIdx.x == 0) sidx[L] = Louter;
}

// ---------------- single-pass decoupled-lookback scan + scatter ----------------
// FINAL (r7 optimum, 180.3us measured). blockDim.x == d (512), ONE channel per
// thread, scalar loads. SCHUNK=64 is the measured optimum of the chunk axis
// (16/32/64/128 -> 216/189/180/183us). z[64] kept ENTIRELY in VGPRs under a
// 128-VGPR cap (__launch_bounds__(512,4)): h is read exactly once
// (nontemporal), no pass-2 re-read. Lookback depth ~2 (P/chunk ~= e^-64 ->
// prodAcc==0 after 2 steps). Thread 0 alone spins (relaxed). Deadlock-free:
// ticket => predecessors resident; aggregate+flag published before any wait.
__global__ __launch_bounds__(512, 4) void scan_lookback_kernel(
        const float* __restrict__ h,
        const float* __restrict__ psel,
        const int* __restrict__ seq,
        const int* __restrict__ sidx,
        float* __restrict__ out,
        float* __restrict__ aggE,   // [NC][d]
        float* __restrict__ aggP,   // [NC]
        int* __restrict__ flags,    // [NC] flags, flags[NC] = ticket
        int L, int d, int Louter, int NC) {
    __shared__ float sh_a[SCHUNK];
    __shared__ float sh_p[SCHUNK];
    __shared__ float sh_A[SCHUNK];   // A_t = prod_{u<=t} a_u
    __shared__ int   sh_j[SCHUNK + 1];
    __shared__ int   sh_g;
    __shared__ float sh_Pbr;

    const int tid = threadIdx.x;
    if (tid == 0) sh_g = atomicAdd(&flags[NC], 1);  // device-scope ticket
    __syncthreads();
    const int g  = sh_g;
    const int t0 = g * SCHUNK;
    const int nt = min(SCHUNK, L - t0);

    // prologue: per-timestep scalars (fused prep) + scatter ranges into LDS
    if (tid < nt) {
        int t = t0 + tid;
        float p = psel[t];
        p = fminf(fmaxf(p, EPSV), 1.0f - EPSV);
        bool start = (t == 0) || (seq[t] != seq[t - 1]);
        sh_a[tid] = start ? 0.0f : (1.0f - p);   // exp(-dt) == 1-p exactly
        sh_p[tid] = p;                           // b_t = p*h
    }
    if (tid <= nt) sh_j[tid] = sidx[t0 + tid];   // sidx[L] sentinel exists
    __syncthreads();

    // wave-0 log-step inclusive prefix-product -> sh_A (6 shfl_up steps)
    if (tid < 64) {
        float v = (tid < nt) ? sh_a[tid] : 1.0f;
#pragma unroll
        for (int off = 1; off < 64; off <<= 1) {
            float w = __shfl_up(v, off);
            if (tid >= off) v *= w;
        }
        sh_A[tid] = v;
    }
    __syncthreads();

    const int c = tid;
    const float* __restrict__ hp = h + (size_t)t0 * d + c;
    const bool full = (nt == SCHUNK);

    // ---- pass 1: local scan fully in registers, h read ONCE (nontemporal) ----
    float z[SCHUNK];
    float st = 0.0f;
    if (full) {
#pragma unroll
        for (int grp = 0; grp < SCHUNK / 8; ++grp) {
            float hb[8];
#pragma unroll
            for (int k = 0; k < 8; ++k)
                hb[k] = __builtin_nontemporal_load(hp + (size_t)(grp * 8 + k) * d);
#pragma unroll
            for (int k = 0; k < 8; ++k) {
                int t = grp * 8 + k;
                st = fmaf(sh_a[t], st, sh_p[t] * hb[k]);
                z[t] = st;                       // static index -> stays in VGPR
            }
        }
    } else {
        for (int t = 0; t < nt; ++t)
            st = fmaf(sh_a[t], st, sh_p[t] * hp[(size_t)t * d]);
    }

    // ---- publish aggregate (relaxed + waitcnt ordering) ----
    agent_store_f(&aggE[(size_t)g * d + c], st);
    __syncthreads();            // drains vmcnt -> all aggE stores complete
    if (tid == 0) {
        agent_store_f(&aggP[g], sh_A[nt - 1]);
        asm volatile("s_waitcnt vmcnt(0)" ::: "memory");  // aggP before flag
        agent_store_i(&flags[g], 1);
    }

    // ---- decoupled lookback: carry = state at end of chunk g-1 ----
    float carry = 0.0f;
    float prodAcc = 1.0f;
    for (int i = g - 1; i >= 0; --i) {
        if (tid == 0) {
            while (agent_load_i(&flags[i]) == 0) __builtin_amdgcn_s_sleep(1);
            sh_Pbr = agent_load_f(&aggP[i]);
        }
        __syncthreads();
        float Pi = sh_Pbr;
        carry = fmaf(prodAcc, agent_load_f(&aggE[(size_t)i * d + c]), carry);
        prodAcc *= Pi;                    // uniform across threads
        __syncthreads();                  // sh_Pbr reused next iteration
        if (prodAcc == 0.0f) break;       // e^-64/chunk -> 0 after ~2 steps
    }

    // ---- pass 2: register-only finalize y_t = A_t*carry + z_t, scatter ----
    if (full) {
#pragma unroll
        for (int t = 0; t < SCHUNK; ++t) {
            float y = fmaf(sh_A[t], carry, z[t]);
            int j0 = max(sh_j[t], 0);
            int j1 = min(sh_j[t + 1], Louter);
            for (int j = j0; j < j1; ++j)
                __builtin_nontemporal_store(y, out + (size_t)j * d + c);
        }
    } else {
        // tail chunk (not hit when L%64==0): rescan with carry folded in
        float s2 = carry;
        for (int t = 0; t < nt; ++t) {
            s2 = fmaf(sh_a[t], s2, sh_p[t] * hp[(size_t)t * d]);
            int j0 = max(sh_j[t], 0);
            int j1 = min(sh_j[t + 1], Louter);
            for (int j = j0; j < j1; ++j)
                out[(size_t)j * d + c] = s2;
        }
    }
}

extern "C" void kernel_launch(void* const* d_in, const int* in_sizes, int n_in,
                              void* d_out, int out_size, void* d_ws, size_t ws_size,
                              hipStream_t stream) {
    const float* h     = (const float*)d_in[0];
    const int*   bflat = (const int*)d_in[1];
    const float* psel  = (const float*)d_in[2];
    const int*   seq   = (const int*)d_in[3];
    float* out = (float*)d_out;

    const int L      = in_sizes[2];          // 131072
    const int Louter = in_sizes[1];          // 262144
    const int d      = in_sizes[0] / L;      // 512

    const int NC = (L + SCHUNK - 1) / SCHUNK;   // 2048
    const int nb = (Louter + 1023) / 1024;      // 256 scan blocks

    // workspace layout (256B-aligned slices) — total ~4.6 MB
    char* ws = (char*)d_ws;
    size_t off = 0;
    auto alloc = [&](size_t bytes) -> void* {
        void* p = ws + off;
        off = (off + bytes + 255) & ~(size_t)255;
        return p;
    };
    float* aggE  = (float*)alloc((size_t)NC * d * 4);
    float* aggP  = (float*)alloc((size_t)NC * 4);
    int*   flags = (int*)alloc((size_t)(NC + 1) * 4);   // +1 = ticket
    int*   bsum  = (int*)alloc((size_t)nb * 4);
    int*   boff  = (int*)alloc((size_t)nb * 4);
    int*   sidx  = (int*)alloc((size_t)(L + 1) * 4);
    (void)ws_size;

    clear_kernel<<<(NC + 1 + 255) / 256, 256, 0, stream>>>(flags, NC + 1);

    scan_sum_kernel<<<nb, 256, 0, stream>>>(bflat, Louter, bsum);
    scan_offsets_kernel<<<1, 1024, 0, stream>>>(bsum, boff, nb);
    scan_emit_kernel<<<nb, 256, 0, stream>>>(bflat, Louter, boff, sidx, L, Louter);

    scan_lookback_kernel<<<NC, d, 0, stream>>>(h, psel, seq, sidx, out,
                                               aggE, aggP, flags,
                                               L, d, Louter, NC);
}